// Round 9
// baseline (279.572 us; speedup 1.0000x reference)
//
#include <hip/hip_runtime.h>
#include <math.h>

// Problem constants
#define NVOX  32768     // 32^3 up-res voxels
#define CIN   64
#define COUT  32
#define KT    27
#define CIT   1728      // CIN*KT
#define PSP   5832      // 18^3 padded half-res spatial

// Workspace layout (float offsets)
#define WS_XT   0                 // fp16[5832][64] channel-last padded x
#define WS_WA   186624            // fp16[216][32][8] deform-W A-frags (K tap-major)
#define WS_WO   214272            // fp16[216][96][8] offset-W A-frags (M padded 81->96)
#define WS_STAT 297216            // [32] sum, [32] sumsq
#define WS_BAR  297280            // [1] spin-barrier counter (zeroed by prep)

typedef __attribute__((ext_vector_type(8))) _Float16 half8;
typedef __attribute__((ext_vector_type(2))) _Float16 half2v;
typedef __attribute__((ext_vector_type(4))) float floatx4;

static __device__ __forceinline__ unsigned dup16(float w) {
    unsigned short b = __builtin_bit_cast(unsigned short, (_Float16)w);
    return (unsigned)b * 0x10001u;
}
static __device__ __forceinline__ half2v u2h2(unsigned u) {
    return __builtin_bit_cast(half2v, u);
}
static __device__ __forceinline__ half8 pk8(half2v a, half2v b, half2v c, half2v d) {
    union { half8 v; half2v p[4]; } u;
    u.p[0] = a; u.p[1] = b; u.p[2] = c; u.p[3] = d;
    return u.v;
}

// ---------------------------------------------------------------------------
// Merged prep (round-4 verified version; block 200 now also zeroes WS_BAR):
//   blocks [0,92):    XT fill via LDS transpose
//   blocks [92,119):  pack wmat  -> WA
//   blocks [119,200): pack w_off -> WO (tap-major K)
//   block  200:       zero stats + barrier counter (every graph replay)
// ---------------------------------------------------------------------------
__global__ __launch_bounds__(256) void prep_all_kernel(
        const float* __restrict__ x, const float* __restrict__ w_off,
        const float* __restrict__ wmat, float* __restrict__ ws) {
    int b = blockIdx.x, t = threadIdx.x;
    if (b < 92) {
        __shared__ _Float16 tile[64][65];
        _Float16* xth = (_Float16*)(ws + WS_XT);
        int tq = t >> 6, lane = t & 63;
        int base = b * 64;
        int cell = base + lane;
        int qw = cell % 18, qh = (cell / 18) % 18, qd = cell / 324;
        bool interior = (cell < PSP) && qd >= 1 && qd <= 16 && qh >= 1 && qh <= 16
                        && qw >= 1 && qw <= 16;
        int xbase = interior ? (((qd - 1) * 16 + (qh - 1)) * 16 + (qw - 1)) : 0;
#pragma unroll
        for (int i = 0; i < 16; i++) {
            int c = tq * 16 + i;
            float v = interior ? x[c * 4096 + xbase] : 0.f;
            tile[lane][c] = (_Float16)v;
        }
        __syncthreads();
#pragma unroll
        for (int i = 0; i < 16; i++) {
            int s = tq * 16 + i;
            int cell2 = base + s;
            if (cell2 < PSP) xth[cell2 * 64 + lane] = tile[s][lane];
        }
    } else if (b < 119) {
        _Float16* wa = (_Float16*)(ws + WS_WA);
        int idx = (b - 92) * 256 + t;           // 0..6911  (kb, o)
        int kb = idx >> 5, o = idx & 31;
        half8 r;
#pragma unroll
        for (int j = 0; j < 8; j++) {
            int kk = kb * 8 + j;                // K index, tap-major
            int tap = kk >> 6, ci = kk & 63;
            r[j] = (_Float16)wmat[o * CIT + ci * 27 + tap];
        }
        *(half8*)(wa + idx * 8) = r;
    } else if (b < 200) {
        _Float16* wo = (_Float16*)(ws + WS_WO);
        int idx = (b - 119) * 256 + t;          // 0..20735 = kb*96 + m
        int kb = idx / 96, m = idx % 96;
        half8 r;
#pragma unroll
        for (int j = 0; j < 8; j++) {
            int kk = kb * 8 + j;
            int tap = kk >> 6, ci = kk & 63;
            float v = (m < 81) ? w_off[(m * 64 + ci) * 27 + tap] : 0.f;
            r[j] = (_Float16)v;
        }
        *(half8*)(wo + idx * 8) = r;
    } else {
        if (t < 66) ws[WS_STAT + t] = 0.f;      // stats (64) + barrier + spare
    }
}

// ---------------------------------------------------------------------------
// Mega kernel: F0 offset GEMM -> P_lds, F1 deform (round-5 body), BN stats,
// then a device-wide spin barrier (grid 1024 == 4/CU x 256 CU, co-resident by
// construction), then BN+ReLU applied IN-REGISTER and the single out write.
// bn_kernel launch and its 8.4 MB out round-trip are deleted.
// ---------------------------------------------------------------------------
#define ACCP(xl, xh, Wx) do { \
    s00 += (Wx) * u2h2((unsigned)(xl).x); s01 += (Wx) * u2h2((unsigned)(xl).y); \
    s02 += (Wx) * u2h2((unsigned)(xl).z); s03 += (Wx) * u2h2((unsigned)(xl).w); \
    s10 += (Wx) * u2h2((unsigned)(xh).x); s11 += (Wx) * u2h2((unsigned)(xh).y); \
    s12 += (Wx) * u2h2((unsigned)(xh).z); s13 += (Wx) * u2h2((unsigned)(xh).w); \
} while (0)

#define DO2(ap, wp) do { \
    int a0_ = (ap) & 0x7fff, a1_ = (int)((((unsigned)(ap)) >> 16) & 0x7fffu); \
    unsigned wl_ = ((unsigned)(wp) & 0xffffu) * 0x10001u; \
    unsigned wh_ = (((unsigned)(wp)) >> 16) * 0x10001u; \
    int4 x0l_ = *(const int4*)(region + (a0_ ^ subLo)); \
    int4 x0h_ = *(const int4*)(region + (a0_ ^ subHi)); \
    int4 x1l_ = *(const int4*)(region + (a1_ ^ subLo)); \
    int4 x1h_ = *(const int4*)(region + (a1_ ^ subHi)); \
    ACCP(x0l_, x0h_, u2h2(wl_)); ACCP(x1l_, x1h_, u2h2(wh_)); \
} while (0)

#define GSLOW(Ax, wf) do { \
    half2v Wq_ = u2h2(dup16(wf)); \
    int4 xl_ = *(const int4*)(xtb + (Ax) + subLo); \
    int4 xh_ = *(const int4*)(xtb + (Ax) + subLo + 64); \
    t00 += Wq_ * u2h2((unsigned)xl_.x); t01 += Wq_ * u2h2((unsigned)xl_.y); \
    t02 += Wq_ * u2h2((unsigned)xl_.z); t03 += Wq_ * u2h2((unsigned)xl_.w); \
    t10 += Wq_ * u2h2((unsigned)xh_.x); t11 += Wq_ * u2h2((unsigned)xh_.y); \
    t12 += Wq_ * u2h2((unsigned)xh_.z); t13 += Wq_ * u2h2((unsigned)xh_.w); \
} while (0)

__global__ __launch_bounds__(256, 4) void mega_kernel(
        const float* __restrict__ b_off, const float* __restrict__ bias,
        const float* __restrict__ gamma, const float* __restrict__ beta,
        float* ws, float* __restrict__ out) {
    __shared__ __align__(16) char shmem[34816];
    char* region = shmem;                                // 25600 B (F1)
    int2* scratch2 = (int2*)(shmem + 25600);             // [4][16][6] int2 (F1)
    _Float16* Pl = (_Float16*)(shmem + 28672);           // [96][32] fp16, 6144 B
    float* pbuf = (float*)shmem;                         // epilogue overlay
    float* rsumS = (float*)(shmem + 8704);               // [32]
    float* rsqS  = (float*)(shmem + 8832);               // [32]

    int tid = threadIdx.x, wave = tid >> 6, lane = tid & 63;
    int col = lane & 15, quad = lane >> 4;
    int bid = blockIdx.x;
    int d0 = (bid >> 6) << 1, h0 = ((bid >> 2) & 15) << 1, w0 = (bid & 3) << 3;

    const char* xtb = (const char*)(ws + WS_XT);
    const half8* wa8 = (const half8*)(ws + WS_WA);
    float* gstat = ws + WS_STAT;

    // ===================== F0: offset GEMM -> P_lds =====================
    {
        int4* ab4 = (int4*)shmem;
        const _Float16* abuf16 = (const _Float16*)shmem;
        const int4* wsrc = (const int4*)(ws + WS_WO);
        int nsub = wave & 1, mh = wave >> 1;             // mh in {0,1}
        int vv = nsub * 16 + col;
        int dA = d0 + (vv >> 4), hA = h0 + ((vv >> 3) & 1), wA = w0 + (vv & 7);

        // prologue: stage tap 0, preload tap 1 into regs
        int4 ra0 = wsrc[tid], ra1 = wsrc[256 + tid], ra2 = wsrc[512 + tid];
        ab4[tid] = ra0; ab4[256 + tid] = ra1; ab4[512 + tid] = ra2;
        ra0 = wsrc[768 + tid]; ra1 = wsrc[768 + 256 + tid]; ra2 = wsrc[768 + 512 + tid];

        // prefetch B for tap 0 (both K-halves)
        int c0;
        {
            int rd = ((dA - 1) >> 1) + 1, rh = ((hA - 1) >> 1) + 1, rw = ((wA - 1) >> 1) + 1;
            c0 = (rd * 18 + rh) * 18 + rw;
        }
        int4 bx0 = *(const int4*)(xtb + c0 * 128 + quad * 16);
        int4 bx1 = *(const int4*)(xtb + c0 * 128 + 64 + quad * 16);
        __syncthreads();

        floatx4 oacc[3];
#pragma unroll
        for (int mt = 0; mt < 3; mt++) oacc[mt] = (floatx4){0.f, 0.f, 0.f, 0.f};

#pragma unroll 1
        for (int tap = 0; tap < 27; tap++) {
            if (tap < 26) {                      // write tap+1 into other buffer
                int4* dst = ab4 + ((tap + 1) & 1) * 768;
                dst[tid] = ra0; dst[256 + tid] = ra1; dst[512 + tid] = ra2;
            }
            if (tap < 25) {                      // preload tap+2
                const int4* s2 = wsrc + (tap + 2) * 768;
                ra0 = s2[tid]; ra1 = s2[256 + tid]; ra2 = s2[512 + tid];
            }
            int4 nbx0 = bx0, nbx1 = bx1;
            if (tap < 26) {                      // prefetch next tap's B
                int tn = tap + 1;
                int kd = tn / 9, r9 = tn - kd * 9, kh2 = r9 / 3, kw2 = r9 - kh2 * 3;
                int rd = ((dA + kd - 1) >> 1) + 1;
                int rh = ((hA + kh2 - 1) >> 1) + 1;
                int rw = ((wA + kw2 - 1) >> 1) + 1;
                int nc = (rd * 18 + rh) * 18 + rw;
                nbx0 = *(const int4*)(xtb + nc * 128 + quad * 16);
                nbx1 = *(const int4*)(xtb + nc * 128 + 64 + quad * 16);
            }
            const _Float16* abh = abuf16 + (tap & 1) * 6144;
            half8 bf0 = __builtin_bit_cast(half8, bx0);
            half8 bf1 = __builtin_bit_cast(half8, bx1);
#pragma unroll
            for (int mt = 0; mt < 3; mt++) {
                half8 a0 = *(const half8*)(abh + quad * 768 + (mh * 48 + mt * 16 + col) * 8);
                oacc[mt] = __builtin_amdgcn_mfma_f32_16x16x32_f16(a0, bf0, oacc[mt], 0, 0, 0);
            }
#pragma unroll
            for (int mt = 0; mt < 3; mt++) {
                half8 a1 = *(const half8*)(abh + (4 + quad) * 768 + (mh * 48 + mt * 16 + col) * 8);
                oacc[mt] = __builtin_amdgcn_mfma_f32_16x16x32_f16(a1, bf1, oacc[mt], 0, 0, 0);
            }
            bx0 = nbx0; bx1 = nbx1;
            __syncthreads();
        }

        // write P slice (each wave owns 48 M-rows x its 16 voxels)
#pragma unroll
        for (int mt = 0; mt < 3; mt++)
#pragma unroll
            for (int r = 0; r < 4; r++) {
                int m = mh * 48 + mt * 16 + quad * 4 + r;
                if (m < 81)
                    Pl[m * 32 + vv] = (_Float16)(oacc[mt][r] + b_off[m]);
            }
        __syncthreads();   // P_lds ready; abuf dead -> region staging may begin
    }

    // ===================== F1: deform (round-5 body, P from LDS) ==========
    int pdlo = (d0 >> 1) - 1, phlo = (h0 >> 1) - 1, pwlo = (w0 >> 1) - 1;

#pragma unroll 1
    for (int it = 0; it < 7; it++) {
        int i = it * 256 + tid;
        if (i < 1600) {
            int r = i >> 3, c16 = i & 7;
            int rd = r / 40, rem = r - rd * 40, rh = rem >> 3, rw = rem & 7;
            int pd = min(max(pdlo + rd, 0), 17);
            int ph = min(max(phlo + rh, 0), 17);
            int pw = min(max(pwlo + rw, 0), 17);
            int cell = (pd * 18 + ph) * 18 + pw;
            int4 vsrc = *(const int4*)(xtb + cell * 128 + c16 * 16);
            int f = (r ^ (r >> 3)) & 7;
            *(int4*)(region + r * 128 + ((c16 ^ f) << 4)) = vsrc;
        }
    }
    __syncthreads();

    int vh = wave & 1, kt = wave >> 1;
    int v = vh * 16 + col;
    int dv = v >> 4, hv = (v >> 3) & 1, wv = v & 7;
    int dcoord = d0 + dv, hcoord = h0 + hv, wcoord = w0 + wv;
    int gvox = dcoord * 1024 + hcoord * 32 + wcoord;
    int tbeg = kt ? 14 : 0, tend = kt ? 27 : 14;
    int subLo = quad * 16, subHi = subLo + 64;
    int bd = quad >> 1, bh = quad & 1;

    floatx4 acc0 = {0.f, 0.f, 0.f, 0.f}, acc1 = {0.f, 0.f, 0.f, 0.f};

    float od = (float)Pl[(3 * tbeg + 0) * 32 + v];
    float oh = (float)Pl[(3 * tbeg + 1) * 32 + v];
    float ow = (float)Pl[(3 * tbeg + 2) * 32 + v];

#pragma unroll 1
    for (int tap = tbeg; tap < tend; tap++) {
        int kd = tap / 9, r9 = tap - kd * 9, kh2 = r9 / 3, kw2 = r9 - kh2 * 3;
        float pdc = (float)(dcoord + kd - 1) + od;
        float phc = (float)(hcoord + kh2 - 1) + oh;
        float pwc = (float)(wcoord + kw2 - 1) + ow;
        float fd0 = floorf(pdc), fh0 = floorf(phc), fw0 = floorf(pwc);
        float fd = pdc - fd0, fh = phc - fh0, fw = pwc - fw0;
        int id = (int)fd0, ih = (int)fh0, iw = (int)fw0;

        int cd0 = ((min(max(id,     -2), 33)) >> 1) + 1;
        int cd1 = ((min(max(id + 1, -2), 33)) >> 1) + 1;
        int ch0 = ((min(max(ih,     -2), 33)) >> 1) + 1;
        int ch1 = ((min(max(ih + 1, -2), 33)) >> 1) + 1;
        int cw0 = ((min(max(iw,     -2), 33)) >> 1) + 1;
        int cw1 = ((min(max(iw + 1, -2), 33)) >> 1) + 1;
        int sd0 = cd0 - pdlo, sd1 = cd1 - pdlo;
        int sh0 = ch0 - phlo, sh1 = ch1 - phlo;
        int sw0 = cw0 - pwlo, sw1 = cw1 - pwlo;
        bool oob = ((unsigned)sd0 > 4u) | ((unsigned)sd1 > 4u)
                 | ((unsigned)sh0 > 4u) | ((unsigned)sh1 > 4u)
                 | ((unsigned)sw0 > 7u) | ((unsigned)sw1 > 7u);

        int sdq = bd ? sd1 : sd0, shq = bh ? sh1 : sh0;
        int rb = (sdq * 5 + shq) * 8;
        int r0 = rb + sw0, r1 = rb + sw1;
        int f0 = (r0 ^ (r0 >> 3)) & 7, f1 = (r1 ^ (r1 >> 3)) & 7;
        int a0 = oob ? 0x8000 : ((r0 << 7) | (f0 << 4));
        int a1 = oob ? 0x8000 : ((r1 << 7) | (f1 << 4));
        float gdw = 1.f - fd, ghw = 1.f - fh, gww = 1.f - fw;
        float wd = bd ? fd : gdw, wh = bh ? fh : ghw;
        float wdh = wd * wh;
        unsigned wb0 = (unsigned)__builtin_bit_cast(unsigned short, (_Float16)(wdh * gww));
        unsigned wb1 = (unsigned)__builtin_bit_cast(unsigned short, (_Float16)(wdh * fw));
        scratch2[(wave * 16 + col) * 6 + quad] =
            make_int2(a0 | (a1 << 16), (int)(wb0 | (wb1 << 16)));

        if (tap + 1 < tend) {
            od = (float)Pl[(3 * tap + 3) * 32 + v];
            oh = (float)Pl[(3 * tap + 4) * 32 + v];
            ow = (float)Pl[(3 * tap + 5) * 32 + v];
        }

        int kb = tap * 8 + quad;
        half8 a00 = wa8[kb * 32 + col];
        half8 a01 = wa8[kb * 32 + 16 + col];
        half8 a10 = wa8[(kb + 4) * 32 + col];
        half8 a11 = wa8[(kb + 4) * 32 + 16 + col];

        const int4* sc = (const int4*)(scratch2 + (wave * 16 + col) * 6);
        int4 p0 = sc[0], p1 = sc[1];

        half2v s00 = {0, 0}, s01 = {0, 0}, s02 = {0, 0}, s03 = {0, 0};
        half2v s10 = {0, 0}, s11 = {0, 0}, s12 = {0, 0}, s13 = {0, 0};
        DO2(p0.x, p0.y); DO2(p0.z, p0.w);
        DO2(p1.x, p1.y); DO2(p1.z, p1.w);

        if (__any((p0.x & 0x8000) != 0)) {
            bool flg = (p0.x & 0x8000) != 0;
            int Rd0 = ((min(max(id,     -2), 33) >> 1) + 1) * (324 * 128);
            int Rd1 = ((min(max(id + 1, -2), 33) >> 1) + 1) * (324 * 128);
            int Rh0 = ((min(max(ih,     -2), 33) >> 1) + 1) * (18 * 128);
            int Rh1 = ((min(max(ih + 1, -2), 33) >> 1) + 1) * (18 * 128);
            int Rw0 = ((min(max(iw,     -2), 33) >> 1) + 1) * 128;
            int Rw1 = ((min(max(iw + 1, -2), 33) >> 1) + 1) * 128;
            half2v t00 = {0,0}, t01 = {0,0}, t02 = {0,0}, t03 = {0,0};
            half2v t10 = {0,0}, t11 = {0,0}, t12 = {0,0}, t13 = {0,0};
            GSLOW(Rd0 + Rh0 + Rw0, gdw * ghw * gww);
            GSLOW(Rd0 + Rh0 + Rw1, gdw * ghw * fw);
            GSLOW(Rd0 + Rh1 + Rw0, gdw * fh  * gww);
            GSLOW(Rd0 + Rh1 + Rw1, gdw * fh  * fw);
            GSLOW(Rd1 + Rh0 + Rw0, fd  * ghw * gww);
            GSLOW(Rd1 + Rh0 + Rw1, fd  * ghw * fw);
            GSLOW(Rd1 + Rh1 + Rw0, fd  * fh  * gww);
            GSLOW(Rd1 + Rh1 + Rw1, fd  * fh  * fw);
            s00 = flg ? t00 : s00; s01 = flg ? t01 : s01;
            s02 = flg ? t02 : s02; s03 = flg ? t03 : s03;
            s10 = flg ? t10 : s10; s11 = flg ? t11 : s11;
            s12 = flg ? t12 : s12; s13 = flg ? t13 : s13;
        }

        half8 bf0 = pk8(s00, s01, s02, s03);
        half8 bf1 = pk8(s10, s11, s12, s13);

        acc0 = __builtin_amdgcn_mfma_f32_16x16x32_f16(a00, bf0, acc0, 0, 0, 0);
        acc1 = __builtin_amdgcn_mfma_f32_16x16x32_f16(a01, bf0, acc1, 0, 0, 0);
        acc0 = __builtin_amdgcn_mfma_f32_16x16x32_f16(a10, bf1, acc0, 0, 0, 0);
        acc1 = __builtin_amdgcn_mfma_f32_16x16x32_f16(a11, bf1, acc1, 0, 0, 0);
    }

    // ---- epilogue: kt-pair reduce, stats; out write deferred past barrier ----
    __syncthreads();
    if (kt == 1) {
#pragma unroll
        for (int r = 0; r < 4; r++) {
            pbuf[((vh * 2 + 0) * 16 + quad * 4 + r) * 17 + col] = acc0[r];
            pbuf[((vh * 2 + 1) * 16 + quad * 4 + r) * 17 + col] = acc1[r];
        }
    }
    if (tid < 64) ((float*)(shmem + 8704))[tid] = 0.f;   // zero rsumS+rsqS
    __syncthreads();
    float v0[4] = {0.f, 0.f, 0.f, 0.f}, v1[4] = {0.f, 0.f, 0.f, 0.f};
    if (kt == 0) {
#pragma unroll
        for (int r = 0; r < 4; r++) {
            int i = quad * 4 + r;
            v0[r] = acc0[r] + pbuf[((vh * 2 + 0) * 16 + i) * 17 + col] + bias[i];
            atomicAdd(&rsumS[i], v0[r]);
            atomicAdd(&rsqS[i], v0[r] * v0[r]);
            v1[r] = acc1[r] + pbuf[((vh * 2 + 1) * 16 + i) * 17 + col] + bias[16 + i];
            atomicAdd(&rsumS[16 + i], v1[r]);
            atomicAdd(&rsqS[16 + i], v1[r] * v1[r]);
        }
    }
    __syncthreads();
    if (tid < COUT) {
        atomicAdd(&gstat[tid], rsumS[tid]);
        atomicAdd(&gstat[COUT + tid], rsqS[tid]);
    }
    __syncthreads();                      // drains this block's gstat atomics

    // ---- device-wide spin barrier (all 1024 blocks co-resident) ----
    if (tid == 0) {
        unsigned* bar = (unsigned*)(ws + WS_BAR);
        __hip_atomic_fetch_add(bar, 1u, __ATOMIC_ACQ_REL, __HIP_MEMORY_SCOPE_AGENT);
        while (__hip_atomic_load(bar, __ATOMIC_ACQUIRE, __HIP_MEMORY_SCOPE_AGENT) < 1024u)
            __builtin_amdgcn_s_sleep(8);
    }
    __syncthreads();

    // ---- BN + ReLU in-register, single out write ----
    float* stats = (float*)shmem;          // pbuf dead; [0..256) reuse
    if (tid < 64)
        stats[tid] = __hip_atomic_load(ws + WS_STAT + tid, __ATOMIC_RELAXED,
                                       __HIP_MEMORY_SCOPE_AGENT);
    __syncthreads();
    if (kt == 0) {
        const float inv = 1.f / 32768.f;
#pragma unroll
        for (int r = 0; r < 4; r++) {
            int i = quad * 4 + r;
            int o0 = i, o1 = 16 + i;
            float m0 = stats[o0] * inv;
            float var0 = stats[32 + o0] * inv - m0 * m0;
            float sc0 = rsqrtf(var0 + 1e-5f) * gamma[o0];
            out[o0 * NVOX + gvox] = fmaxf((v0[r] - m0) * sc0 + beta[o0], 0.f);
            float m1 = stats[o1] * inv;
            float var1 = stats[32 + o1] * inv - m1 * m1;
            float sc1 = rsqrtf(var1 + 1e-5f) * gamma[o1];
            out[o1 * NVOX + gvox] = fmaxf((v1[r] - m1) * sc1 + beta[o1], 0.f);
        }
    }
}

// ---------------------------------------------------------------------------
extern "C" void kernel_launch(void* const* d_in, const int* in_sizes, int n_in,
                              void* d_out, int out_size, void* d_ws, size_t ws_size,
                              hipStream_t stream) {
    const float* x     = (const float*)d_in[0];
    const float* w_off = (const float*)d_in[1];
    const float* b_off = (const float*)d_in[2];
    const float* wmat  = (const float*)d_in[3];
    const float* bias  = (const float*)d_in[4];
    const float* gamma = (const float*)d_in[5];
    const float* beta  = (const float*)d_in[6];
    float* ws  = (float*)d_ws;
    float* out = (float*)d_out;

    prep_all_kernel<<<201, 256, 0, stream>>>(x, w_off, wmat, ws);
    mega_kernel<<<1024, 256, 0, stream>>>(b_off, bias, gamma, beta, ws, out);
}

// Round 10
// 134.505 us; speedup vs baseline: 2.0785x; 2.0785x over previous
//
#include <hip/hip_runtime.h>
#include <math.h>

// Problem constants
#define NVOX  32768     // 32^3 up-res voxels
#define CIN   64
#define COUT  32
#define KT    27
#define CIT   1728      // CIN*KT
#define PSP   5832      // 18^3 padded half-res spatial

// Workspace layout (float offsets)
#define WS_XT   0                 // fp16[5832][64] channel-last padded x
#define WS_WA   186624            // fp16[216][32][8] deform-W A-frags (K tap-major)
#define WS_W2   214272            // fp16[8][64][96][8] parity-collapsed offset-W frags
#define WS_STAT 410880            // [32] sum, [32] sumsq

typedef __attribute__((ext_vector_type(8))) _Float16 half8;
typedef __attribute__((ext_vector_type(2))) _Float16 half2v;
typedef __attribute__((ext_vector_type(4))) float floatx4;

static __device__ __forceinline__ unsigned dup16(float w) {
    unsigned short b = __builtin_bit_cast(unsigned short, (_Float16)w);
    return (unsigned)b * 0x10001u;
}
static __device__ __forceinline__ half2v u2h2(unsigned u) {
    return __builtin_bit_cast(half2v, u);
}
static __device__ __forceinline__ half8 pk8(half2v a, half2v b, half2v c, half2v d) {
    union { half8 v; half2v p[4]; } u;
    u.p[0] = a; u.p[1] = b; u.p[2] = c; u.p[3] = d;
    return u.v;
}

// ---------------------------------------------------------------------------
// Merged prep (round-5 verified version):
//   blocks [0,92):    XT fill via LDS transpose
//   blocks [92,119):  pack wmat -> WA
//   blocks [119,311): pack parity-collapsed offset weights -> W2
//   block  311:       zero stats
// ---------------------------------------------------------------------------
__global__ __launch_bounds__(256) void prep_all_kernel(
        const float* __restrict__ x, const float* __restrict__ w_off,
        const float* __restrict__ wmat, float* __restrict__ ws) {
    int b = blockIdx.x, t = threadIdx.x;
    if (b < 92) {
        __shared__ _Float16 tile[64][65];
        _Float16* xth = (_Float16*)(ws + WS_XT);
        int tq = t >> 6, lane = t & 63;
        int base = b * 64;
        int cell = base + lane;
        int qw = cell % 18, qh = (cell / 18) % 18, qd = cell / 324;
        bool interior = (cell < PSP) && qd >= 1 && qd <= 16 && qh >= 1 && qh <= 16
                        && qw >= 1 && qw <= 16;
        int xbase = interior ? (((qd - 1) * 16 + (qh - 1)) * 16 + (qw - 1)) : 0;
#pragma unroll
        for (int i = 0; i < 16; i++) {
            int c = tq * 16 + i;
            float v = interior ? x[c * 4096 + xbase] : 0.f;
            tile[lane][c] = (_Float16)v;
        }
        __syncthreads();
#pragma unroll
        for (int i = 0; i < 16; i++) {
            int s = tq * 16 + i;
            int cell2 = base + s;
            if (cell2 < PSP) xth[cell2 * 64 + lane] = tile[s][lane];
        }
    } else if (b < 119) {
        _Float16* wa = (_Float16*)(ws + WS_WA);
        int idx = (b - 92) * 256 + t;           // 0..6911  (kb, o)
        int kb = idx >> 5, o = idx & 31;
        half8 r;
#pragma unroll
        for (int j = 0; j < 8; j++) {
            int kk = kb * 8 + j;                // K index, tap-major
            int tap = kk >> 6, ci = kk & 63;
            r[j] = (_Float16)wmat[o * CIT + ci * 27 + tap];
        }
        *(half8*)(wa + idx * 8) = r;
    } else if (b < 311) {
        _Float16* w2 = (_Float16*)(ws + WS_W2);
        int idx = (b - 119) * 256 + t;          // 0..49151 = (pi*64 + kb)*96 + m
        int pi = idx / 6144;
        int rem = idx - pi * 6144;
        int kb = rem / 96, m = rem - (rem / 96) * 96;
        int pid = pi >> 2, pih = (pi >> 1) & 1, piw = pi & 1;
        half8 r;
#pragma unroll
        for (int j = 0; j < 8; j++) {
            int kk = kb * 8 + j;                // K in [0,512)
            int tap2 = kk >> 6, ci = kk & 63;
            int cd = tap2 >> 2, ch = (tap2 >> 1) & 1, cw = tap2 & 1;
            int bd = pid ? (cd ? 2 : 0) : cd;
            int nd = pid ? (cd ? 1 : 2) : (cd ? 2 : 1);
            int bh = pih ? (ch ? 2 : 0) : ch;
            int nh = pih ? (ch ? 1 : 2) : (ch ? 2 : 1);
            int bw = piw ? (cw ? 2 : 0) : cw;
            int nw = piw ? (cw ? 1 : 2) : (cw ? 2 : 1);
            float s = 0.f;
            if (m < 81) {
                const float* wp = w_off + (m * 64 + ci) * 27;
                for (int a = 0; a < nd; a++)
                    for (int bb = 0; bb < nh; bb++)
                        for (int c = 0; c < nw; c++)
                            s += wp[(bd + a) * 9 + (bh + bb) * 3 + (bw + c)];
            }
            r[j] = (_Float16)s;
        }
        *(half8*)(w2 + idx * 8) = r;
    } else {
        if (t < 64) ws[WS_STAT + t] = 0.f;
    }
}

// ---------------------------------------------------------------------------
// Fused kernel, parity-tiled: block = parity pi x 2x2x8 half-res cell tile
// (32 same-parity voxels). F0 = R5-verified parity-collapsed offset GEMM
// (K=512) -> P_lds. F1 = R5-verified deform body on a 4x4x10 region
// (exact-bounds, no clamp). Exact global fallback when sample leaves region.
// LDS: F0 abuf dbuf [0,24576) ; F1 region [0,20480) + scratch2 [20480,23552);
//      Pl [24576,30720) spans both; epilogue pbuf/rsum overlay region.
// ---------------------------------------------------------------------------
#define ACCP(xl, xh, Wx) do { \
    s00 += (Wx) * u2h2((unsigned)(xl).x); s01 += (Wx) * u2h2((unsigned)(xl).y); \
    s02 += (Wx) * u2h2((unsigned)(xl).z); s03 += (Wx) * u2h2((unsigned)(xl).w); \
    s10 += (Wx) * u2h2((unsigned)(xh).x); s11 += (Wx) * u2h2((unsigned)(xh).y); \
    s12 += (Wx) * u2h2((unsigned)(xh).z); s13 += (Wx) * u2h2((unsigned)(xh).w); \
} while (0)

#define DO2(ap, wp) do { \
    int a0_ = (ap) & 0x7fff, a1_ = (int)((((unsigned)(ap)) >> 16) & 0x7fffu); \
    unsigned wl_ = ((unsigned)(wp) & 0xffffu) * 0x10001u; \
    unsigned wh_ = (((unsigned)(wp)) >> 16) * 0x10001u; \
    int4 x0l_ = *(const int4*)(region + (a0_ ^ subLo)); \
    int4 x0h_ = *(const int4*)(region + (a0_ ^ subHi)); \
    int4 x1l_ = *(const int4*)(region + (a1_ ^ subLo)); \
    int4 x1h_ = *(const int4*)(region + (a1_ ^ subHi)); \
    ACCP(x0l_, x0h_, u2h2(wl_)); ACCP(x1l_, x1h_, u2h2(wh_)); \
} while (0)

#define GSLOW(Ax, wf) do { \
    half2v Wq_ = u2h2(dup16(wf)); \
    int4 xl_ = *(const int4*)(xtb + (Ax) + subLo); \
    int4 xh_ = *(const int4*)(xtb + (Ax) + subLo + 64); \
    t00 += Wq_ * u2h2((unsigned)xl_.x); t01 += Wq_ * u2h2((unsigned)xl_.y); \
    t02 += Wq_ * u2h2((unsigned)xl_.z); t03 += Wq_ * u2h2((unsigned)xl_.w); \
    t10 += Wq_ * u2h2((unsigned)xh_.x); t11 += Wq_ * u2h2((unsigned)xh_.y); \
    t12 += Wq_ * u2h2((unsigned)xh_.z); t13 += Wq_ * u2h2((unsigned)xh_.w); \
} while (0)

__global__ __launch_bounds__(256, 4) void fused_kernel(
        const float* __restrict__ b_off, const float* __restrict__ bias,
        float* ws, float* __restrict__ out) {
    __shared__ __align__(16) char shmem[30720];
    char* region = shmem;                                // [0,20480) F1
    int2* scratch2 = (int2*)(shmem + 20480);             // [20480,23552) F1
    _Float16* Pl = (_Float16*)(shmem + 24576);           // [96][32] fp16
    float* pbuf = (float*)shmem;                         // epilogue overlay
    float* rsumS = (float*)(shmem + 8704);               // [32]
    float* rsqS  = (float*)(shmem + 8832);               // [32]

    int tid = threadIdx.x, wave = tid >> 6, lane = tid & 63;
    int col = lane & 15, quad = lane >> 4;
    int bid = blockIdx.x;
    int pi = bid >> 7, tile = bid & 127;
    int pid = pi >> 2, pih = (pi >> 1) & 1, piw = pi & 1;
    int qd0 = (tile >> 4) << 1;                          // 0..14 step 2
    int qh0 = ((tile >> 1) & 7) << 1;                    // 0..14 step 2
    int qw0 = (tile & 1) << 3;                           // 0 or 8

    const char* xtb = (const char*)(ws + WS_XT);
    const half8* wa8 = (const half8*)(ws + WS_WA);
    float* gstat = ws + WS_STAT;

    // ===================== F0: parity-collapsed offset GEMM -> P_lds ======
    {
        int4* ab4 = (int4*)shmem;                        // dbuf [0,24576)
        const _Float16* abuf16 = (const _Float16*)shmem;
        const int4* wsrc = (const int4*)(ws + WS_W2) + pi * 6144;
        int nsub = wave & 1, kh = wave >> 1;
        int vv = nsub * 16 + col;
        int qdv = qd0 + (vv >> 4), qhv = qh0 + ((vv >> 3) & 1), qwv = qw0 + (vv & 7);

        // preload all 8 B-frags (independent -> full ILP, none in loop)
        int4 bx[8];
#pragma unroll
        for (int tap = 0; tap < 8; tap++) {
            int cd = tap >> 2, ch = (tap >> 1) & 1, cw = tap & 1;
            int cell = ((qdv + cd + pid) * 18 + (qhv + ch + pih)) * 18 + (qwv + cw + piw);
            bx[tap] = *(const int4*)(xtb + cell * 128 + kh * 64 + quad * 16);
        }

        // prologue: stage tap 0, preload tap 1
        int4 ra0 = wsrc[tid], ra1 = wsrc[256 + tid], ra2 = wsrc[512 + tid];
        ab4[tid] = ra0; ab4[256 + tid] = ra1; ab4[512 + tid] = ra2;
        ra0 = wsrc[768 + tid]; ra1 = wsrc[768 + 256 + tid]; ra2 = wsrc[768 + 512 + tid];
        __syncthreads();

        floatx4 acc[6];
#pragma unroll
        for (int mt = 0; mt < 6; mt++) acc[mt] = (floatx4){0.f, 0.f, 0.f, 0.f};

        int fb = (kh * 4 + quad) * 768 + col * 8;

#pragma unroll
        for (int tap = 0; tap < 8; tap++) {
            if (tap < 7) {
                int4* dst = ab4 + ((tap + 1) & 1) * 768;
                dst[tid] = ra0; dst[256 + tid] = ra1; dst[512 + tid] = ra2;
            }
            if (tap < 6) {
                const int4* s2 = wsrc + (tap + 2) * 768;
                ra0 = s2[tid]; ra1 = s2[256 + tid]; ra2 = s2[512 + tid];
            }
            half8 bfrag = __builtin_bit_cast(half8, bx[tap]);
            const _Float16* abh = abuf16 + (tap & 1) * 6144;
#pragma unroll
            for (int mt = 0; mt < 6; mt++) {
                half8 af = *(const half8*)(abh + fb + mt * 128);
                acc[mt] = __builtin_amdgcn_mfma_f32_16x16x32_f16(af, bfrag, acc[mt], 0, 0, 0);
            }
            __syncthreads();
        }

        // kh reduce through LDS (abuf dead after loop-end barrier)
        float* red = (float*)shmem;                      // [(nsub*96+m)*17+col]
        if (kh == 1) {
#pragma unroll
            for (int mt = 0; mt < 6; mt++)
#pragma unroll
                for (int r = 0; r < 4; r++)
                    red[(nsub * 96 + mt * 16 + quad * 4 + r) * 17 + col] = acc[mt][r];
        }
        __syncthreads();
        if (kh == 0) {
#pragma unroll
            for (int mt = 0; mt < 6; mt++)
#pragma unroll
                for (int r = 0; r < 4; r++) {
                    int m = mt * 16 + quad * 4 + r;
                    if (m < 81)
                        Pl[m * 32 + vv] = (_Float16)(acc[mt][r]
                                         + red[(nsub * 96 + m) * 17 + col] + b_off[m]);
                }
        }
        __syncthreads();   // P_lds ready; red/abuf dead -> region staging
    }

    // ===================== F1: deform on 4x4x10 region ====================
    // region rows r = (rd*4+rh)*10+rw, padded cells (qd0+rd, qh0+rh, qw0+rw),
    // rd,rh in [0,4), rw in [0,10) — exact bounds, no clamping needed.
#pragma unroll 1
    for (int it = 0; it < 5; it++) {
        int i = it * 256 + tid;                          // 1280 = 5*256 exact
        int r = i >> 3, c16 = i & 7;
        int rd = r / 40, rem = r - rd * 40, rh = rem / 10, rw = rem - rh * 10;
        int cell = ((qd0 + rd) * 18 + (qh0 + rh)) * 18 + (qw0 + rw);
        int4 vsrc = *(const int4*)(xtb + cell * 128 + c16 * 16);
        int f = (r ^ (r >> 3)) & 7;
        *(int4*)(region + r * 128 + ((c16 ^ f) << 4)) = vsrc;
    }
    __syncthreads();

    int vh = wave & 1, kt = wave >> 1;
    int v = vh * 16 + col;
    int qdv = qd0 + (v >> 4), qhv = qh0 + ((v >> 3) & 1), qwv = qw0 + (v & 7);
    int dcoord = 2 * qdv + pid, hcoord = 2 * qhv + pih, wcoord = 2 * qwv + piw;
    int gvox = dcoord * 1024 + hcoord * 32 + wcoord;
    int tbeg = kt ? 14 : 0, tend = kt ? 27 : 14;
    int subLo = quad * 16, subHi = subLo + 64;
    int bd = quad >> 1, bh = quad & 1;

    floatx4 acc0 = {0.f, 0.f, 0.f, 0.f}, acc1 = {0.f, 0.f, 0.f, 0.f};

    float od = (float)Pl[(3 * tbeg + 0) * 32 + v];
    float oh = (float)Pl[(3 * tbeg + 1) * 32 + v];
    float ow = (float)Pl[(3 * tbeg + 2) * 32 + v];

#pragma unroll 1
    for (int tap = tbeg; tap < tend; tap++) {
        int kd = tap / 9, r9 = tap - kd * 9, kh2 = r9 / 3, kw2 = r9 - kh2 * 3;
        float pdc = (float)(dcoord + kd - 1) + od;
        float phc = (float)(hcoord + kh2 - 1) + oh;
        float pwc = (float)(wcoord + kw2 - 1) + ow;
        float fd0 = floorf(pdc), fh0 = floorf(phc), fw0 = floorf(pwc);
        float fd = pdc - fd0, fh = phc - fh0, fw = pwc - fw0;
        int id = (int)fd0, ih = (int)fh0, iw = (int)fw0;

        int cd0 = ((min(max(id,     -2), 33)) >> 1) + 1;
        int cd1 = ((min(max(id + 1, -2), 33)) >> 1) + 1;
        int ch0 = ((min(max(ih,     -2), 33)) >> 1) + 1;
        int ch1 = ((min(max(ih + 1, -2), 33)) >> 1) + 1;
        int cw0 = ((min(max(iw,     -2), 33)) >> 1) + 1;
        int cw1 = ((min(max(iw + 1, -2), 33)) >> 1) + 1;
        int sd0 = cd0 - qd0, sd1 = cd1 - qd0;
        int sh0 = ch0 - qh0, sh1 = ch1 - qh0;
        int sw0 = cw0 - qw0, sw1 = cw1 - qw0;
        bool oob = ((unsigned)sd0 > 3u) | ((unsigned)sd1 > 3u)
                 | ((unsigned)sh0 > 3u) | ((unsigned)sh1 > 3u)
                 | ((unsigned)sw0 > 9u) | ((unsigned)sw1 > 9u);

        // this lane builds corners (bd,bh,0) and (bd,bh,1)
        int sdq = bd ? sd1 : sd0, shq = bh ? sh1 : sh0;
        int rb = (sdq * 4 + shq) * 10;
        int r0 = rb + sw0, r1 = rb + sw1;
        int f0 = (r0 ^ (r0 >> 3)) & 7, f1 = (r1 ^ (r1 >> 3)) & 7;
        int a0 = oob ? 0x8000 : ((r0 << 7) | (f0 << 4));
        int a1 = oob ? 0x8000 : ((r1 << 7) | (f1 << 4));
        float gdw = 1.f - fd, ghw = 1.f - fh, gww = 1.f - fw;
        float wd = bd ? fd : gdw, wh = bh ? fh : ghw;
        float wdh = wd * wh;
        unsigned wb0 = (unsigned)__builtin_bit_cast(unsigned short, (_Float16)(wdh * gww));
        unsigned wb1 = (unsigned)__builtin_bit_cast(unsigned short, (_Float16)(wdh * fw));
        scratch2[(wave * 16 + col) * 6 + quad] =
            make_int2(a0 | (a1 << 16), (int)(wb0 | (wb1 << 16)));

        if (tap + 1 < tend) {
            od = (float)Pl[(3 * tap + 3) * 32 + v];
            oh = (float)Pl[(3 * tap + 4) * 32 + v];
            ow = (float)Pl[(3 * tap + 5) * 32 + v];
        }

        int kb = tap * 8 + quad;
        half8 a00 = wa8[kb * 32 + col];
        half8 a01 = wa8[kb * 32 + 16 + col];
        half8 a10 = wa8[(kb + 4) * 32 + col];
        half8 a11 = wa8[(kb + 4) * 32 + 16 + col];

        const int4* sc = (const int4*)(scratch2 + (wave * 16 + col) * 6);
        int4 p0 = sc[0], p1 = sc[1];

        half2v s00 = {0, 0}, s01 = {0, 0}, s02 = {0, 0}, s03 = {0, 0};
        half2v s10 = {0, 0}, s11 = {0, 0}, s12 = {0, 0}, s13 = {0, 0};
        DO2(p0.x, p0.y); DO2(p0.z, p0.w);
        DO2(p1.x, p1.y); DO2(p1.z, p1.w);

        if (__any((p0.x & 0x8000) != 0)) {
            bool flg = (p0.x & 0x8000) != 0;
            int Rd0 = ((min(max(id,     -2), 33) >> 1) + 1) * (324 * 128);
            int Rd1 = ((min(max(id + 1, -2), 33) >> 1) + 1) * (324 * 128);
            int Rh0 = ((min(max(ih,     -2), 33) >> 1) + 1) * (18 * 128);
            int Rh1 = ((min(max(ih + 1, -2), 33) >> 1) + 1) * (18 * 128);
            int Rw0 = ((min(max(iw,     -2), 33) >> 1) + 1) * 128;
            int Rw1 = ((min(max(iw + 1, -2), 33) >> 1) + 1) * 128;
            half2v t00 = {0,0}, t01 = {0,0}, t02 = {0,0}, t03 = {0,0};
            half2v t10 = {0,0}, t11 = {0,0}, t12 = {0,0}, t13 = {0,0};
            GSLOW(Rd0 + Rh0 + Rw0, gdw * ghw * gww);
            GSLOW(Rd0 + Rh0 + Rw1, gdw * ghw * fw);
            GSLOW(Rd0 + Rh1 + Rw0, gdw * fh  * gww);
            GSLOW(Rd0 + Rh1 + Rw1, gdw * fh  * fw);
            GSLOW(Rd1 + Rh0 + Rw0, fd  * ghw * gww);
            GSLOW(Rd1 + Rh0 + Rw1, fd  * ghw * fw);
            GSLOW(Rd1 + Rh1 + Rw0, fd  * fh  * gww);
            GSLOW(Rd1 + Rh1 + Rw1, fd  * fh  * fw);
            s00 = flg ? t00 : s00; s01 = flg ? t01 : s01;
            s02 = flg ? t02 : s02; s03 = flg ? t03 : s03;
            s10 = flg ? t10 : s10; s11 = flg ? t11 : s11;
            s12 = flg ? t12 : s12; s13 = flg ? t13 : s13;
        }

        half8 bf0 = pk8(s00, s01, s02, s03);
        half8 bf1 = pk8(s10, s11, s12, s13);

        acc0 = __builtin_amdgcn_mfma_f32_16x16x32_f16(a00, bf0, acc0, 0, 0, 0);
        acc1 = __builtin_amdgcn_mfma_f32_16x16x32_f16(a01, bf0, acc1, 0, 0, 0);
        acc0 = __builtin_amdgcn_mfma_f32_16x16x32_f16(a10, bf1, acc0, 0, 0, 0);
        acc1 = __builtin_amdgcn_mfma_f32_16x16x32_f16(a11, bf1, acc1, 0, 0, 0);
    }

    // ---- epilogue: region dead -> overlay pbuf/rsum ----
    __syncthreads();
    if (kt == 1) {
#pragma unroll
        for (int r = 0; r < 4; r++) {
            pbuf[((vh * 2 + 0) * 16 + quad * 4 + r) * 17 + col] = acc0[r];
            pbuf[((vh * 2 + 1) * 16 + quad * 4 + r) * 17 + col] = acc1[r];
        }
    }
    if (tid < 64) ((float*)(shmem + 8704))[tid] = 0.f;   // zero rsumS+rsqS
    __syncthreads();
    if (kt == 0) {
#pragma unroll
        for (int r = 0; r < 4; r++) {
            int i = quad * 4 + r;
            int o0 = i;
            float v0 = acc0[r] + pbuf[((vh * 2 + 0) * 16 + i) * 17 + col] + bias[o0];
            out[o0 * NVOX + gvox] = v0;
            atomicAdd(&rsumS[o0], v0);
            atomicAdd(&rsqS[o0], v0 * v0);
            int o1 = 16 + i;
            float v1 = acc1[r] + pbuf[((vh * 2 + 1) * 16 + i) * 17 + col] + bias[o1];
            out[o1 * NVOX + gvox] = v1;
            atomicAdd(&rsumS[o1], v1);
            atomicAdd(&rsqS[o1], v1 * v1);
        }
    }
    __syncthreads();
    if (tid < COUT) {
        atomicAdd(&gstat[tid], rsumS[tid]);
        atomicAdd(&gstat[COUT + tid], rsqS[tid]);
    }
}

// ---------------------------------------------------------------------------
// BN finalize + ReLU, in-place on d_out (unchanged).
// ---------------------------------------------------------------------------
__global__ void bn_kernel(const float* __restrict__ ws,
                          const float* __restrict__ gamma,
                          const float* __restrict__ beta,
                          float* out) {
    int i = blockIdx.x * 256 + threadIdx.x;
    int o = i >> 15;
    const float* gstat = ws + WS_STAT;
    const float inv = 1.f / 32768.f;
    float mean = gstat[o] * inv;
    float var  = gstat[COUT + o] * inv - mean * mean;
    float sc   = rsqrtf(var + 1e-5f) * gamma[o];
    float v = (out[i] - mean) * sc + beta[o];
    out[i] = fmaxf(v, 0.f);
}

// ---------------------------------------------------------------------------
extern "C" void kernel_launch(void* const* d_in, const int* in_sizes, int n_in,
                              void* d_out, int out_size, void* d_ws, size_t ws_size,
                              hipStream_t stream) {
    const float* x     = (const float*)d_in[0];
    const float* w_off = (const float*)d_in[1];
    const float* b_off = (const float*)d_in[2];
    const float* wmat  = (const float*)d_in[3];
    const float* bias  = (const float*)d_in[4];
    const float* gamma = (const float*)d_in[5];
    const float* beta  = (const float*)d_in[6];
    float* ws  = (float*)d_ws;
    float* out = (float*)d_out;

    prep_all_kernel<<<312, 256, 0, stream>>>(x, w_off, wmat, ws);
    fused_kernel<<<1024, 256, 0, stream>>>(b_off, bias, ws, out);
    bn_kernel<<<4096, 256, 0, stream>>>(ws, gamma, beta, out);
}

// Round 11
// 134.225 us; speedup vs baseline: 2.0829x; 1.0021x over previous
//
#include <hip/hip_runtime.h>
#include <math.h>

// Problem constants
#define NVOX  32768     // 32^3 up-res voxels
#define CIN   64
#define COUT  32
#define KT    27
#define CIT   1728      // CIN*KT
#define PSP   5832      // 18^3 padded half-res spatial

// Workspace layout (float offsets)
#define WS_XT   0                 // fp16[5832][64] channel-last padded x
#define WS_WA   186624            // fp16[216][32][8] deform-W A-frags (K tap-major)
#define WS_W2   214272            // fp16[8][64][96][8] parity-collapsed offset-W frags
#define WS_STAT 410880            // [32] sum, [32] sumsq

typedef __attribute__((ext_vector_type(8))) _Float16 half8;
typedef __attribute__((ext_vector_type(2))) _Float16 half2v;
typedef __attribute__((ext_vector_type(4))) float floatx4;

static __device__ __forceinline__ unsigned dup16(float w) {
    unsigned short b = __builtin_bit_cast(unsigned short, (_Float16)w);
    return (unsigned)b * 0x10001u;
}
static __device__ __forceinline__ half2v u2h2(unsigned u) {
    return __builtin_bit_cast(half2v, u);
}
static __device__ __forceinline__ half8 pk8(half2v a, half2v b, half2v c, half2v d) {
    union { half8 v; half2v p[4]; } u;
    u.p[0] = a; u.p[1] = b; u.p[2] = c; u.p[3] = d;
    return u.v;
}

// ---------------------------------------------------------------------------
// Merged prep (round-5 verified version, unchanged):
//   blocks [0,92):    XT fill via LDS transpose
//   blocks [92,119):  pack wmat -> WA
//   blocks [119,311): pack parity-collapsed offset weights -> W2
//   block  311:       zero stats
// ---------------------------------------------------------------------------
__global__ __launch_bounds__(256) void prep_all_kernel(
        const float* __restrict__ x, const float* __restrict__ w_off,
        const float* __restrict__ wmat, float* __restrict__ ws) {
    int b = blockIdx.x, t = threadIdx.x;
    if (b < 92) {
        __shared__ _Float16 tile[64][65];
        _Float16* xth = (_Float16*)(ws + WS_XT);
        int tq = t >> 6, lane = t & 63;
        int base = b * 64;
        int cell = base + lane;
        int qw = cell % 18, qh = (cell / 18) % 18, qd = cell / 324;
        bool interior = (cell < PSP) && qd >= 1 && qd <= 16 && qh >= 1 && qh <= 16
                        && qw >= 1 && qw <= 16;
        int xbase = interior ? (((qd - 1) * 16 + (qh - 1)) * 16 + (qw - 1)) : 0;
#pragma unroll
        for (int i = 0; i < 16; i++) {
            int c = tq * 16 + i;
            float v = interior ? x[c * 4096 + xbase] : 0.f;
            tile[lane][c] = (_Float16)v;
        }
        __syncthreads();
#pragma unroll
        for (int i = 0; i < 16; i++) {
            int s = tq * 16 + i;
            int cell2 = base + s;
            if (cell2 < PSP) xth[cell2 * 64 + lane] = tile[s][lane];
        }
    } else if (b < 119) {
        _Float16* wa = (_Float16*)(ws + WS_WA);
        int idx = (b - 92) * 256 + t;           // 0..6911  (kb, o)
        int kb = idx >> 5, o = idx & 31;
        half8 r;
#pragma unroll
        for (int j = 0; j < 8; j++) {
            int kk = kb * 8 + j;                // K index, tap-major
            int tap = kk >> 6, ci = kk & 63;
            r[j] = (_Float16)wmat[o * CIT + ci * 27 + tap];
        }
        *(half8*)(wa + idx * 8) = r;
    } else if (b < 311) {
        _Float16* w2 = (_Float16*)(ws + WS_W2);
        int idx = (b - 119) * 256 + t;          // 0..49151 = (pi*64 + kb)*96 + m
        int pi = idx / 6144;
        int rem = idx - pi * 6144;
        int kb = rem / 96, m = rem - (rem / 96) * 96;
        int pid = pi >> 2, pih = (pi >> 1) & 1, piw = pi & 1;
        half8 r;
#pragma unroll
        for (int j = 0; j < 8; j++) {
            int kk = kb * 8 + j;                // K in [0,512)
            int tap2 = kk >> 6, ci = kk & 63;
            int cd = tap2 >> 2, ch = (tap2 >> 1) & 1, cw = tap2 & 1;
            int bd = pid ? (cd ? 2 : 0) : cd;
            int nd = pid ? (cd ? 1 : 2) : (cd ? 2 : 1);
            int bh = pih ? (ch ? 2 : 0) : ch;
            int nh = pih ? (ch ? 1 : 2) : (ch ? 2 : 1);
            int bw = piw ? (cw ? 2 : 0) : cw;
            int nw = piw ? (cw ? 1 : 2) : (cw ? 2 : 1);
            float s = 0.f;
            if (m < 81) {
                const float* wp = w_off + (m * 64 + ci) * 27;
                for (int a = 0; a < nd; a++)
                    for (int bb = 0; bb < nh; bb++)
                        for (int c = 0; c < nw; c++)
                            s += wp[(bd + a) * 9 + (bh + bb) * 3 + (bw + c)];
            }
            r[j] = (_Float16)s;
        }
        *(half8*)(w2 + idx * 8) = r;
    } else {
        if (t < 64) ws[WS_STAT + t] = 0.f;
    }
}

// ---------------------------------------------------------------------------
// Fused kernel, parity-tiled (R10 verified structure). Round-11 change:
// region rows stored at 176 B stride (11 chunks for 10 used). Bank-quad of
// chunk c in row r = (11r + c) mod 8; 11 === 3 (mod 8) so consecutive sw
// rotate by 3 -> the wave's 8 w-lanes hit 8 distinct bank-quads, h-pair
// offsets by 6 -> worst case 2-way (free, m136). No XOR swizzle needed:
// addresses are plain r*176 + chan*16 (ADD, not XOR).
// LDS: F0 abuf dbuf [0,24576) ; F1 region [0,28160) + scratch2 [28160,31232);
//      Pl [31232,37376) spans both; epilogue pbuf/rsum overlay region.
// ---------------------------------------------------------------------------
#define ACCP(xl, xh, Wx) do { \
    s00 += (Wx) * u2h2((unsigned)(xl).x); s01 += (Wx) * u2h2((unsigned)(xl).y); \
    s02 += (Wx) * u2h2((unsigned)(xl).z); s03 += (Wx) * u2h2((unsigned)(xl).w); \
    s10 += (Wx) * u2h2((unsigned)(xh).x); s11 += (Wx) * u2h2((unsigned)(xh).y); \
    s12 += (Wx) * u2h2((unsigned)(xh).z); s13 += (Wx) * u2h2((unsigned)(xh).w); \
} while (0)

#define DO2(ap, wp) do { \
    int a0_ = (ap) & 0x7fff, a1_ = (int)((((unsigned)(ap)) >> 16) & 0x7fffu); \
    unsigned wl_ = ((unsigned)(wp) & 0xffffu) * 0x10001u; \
    unsigned wh_ = (((unsigned)(wp)) >> 16) * 0x10001u; \
    int4 x0l_ = *(const int4*)(region + a0_ + subLo); \
    int4 x0h_ = *(const int4*)(region + a0_ + subHi); \
    int4 x1l_ = *(const int4*)(region + a1_ + subLo); \
    int4 x1h_ = *(const int4*)(region + a1_ + subHi); \
    ACCP(x0l_, x0h_, u2h2(wl_)); ACCP(x1l_, x1h_, u2h2(wh_)); \
} while (0)

#define GSLOW(Ax, wf) do { \
    half2v Wq_ = u2h2(dup16(wf)); \
    int4 xl_ = *(const int4*)(xtb + (Ax) + subLo); \
    int4 xh_ = *(const int4*)(xtb + (Ax) + subLo + 64); \
    t00 += Wq_ * u2h2((unsigned)xl_.x); t01 += Wq_ * u2h2((unsigned)xl_.y); \
    t02 += Wq_ * u2h2((unsigned)xl_.z); t03 += Wq_ * u2h2((unsigned)xl_.w); \
    t10 += Wq_ * u2h2((unsigned)xh_.x); t11 += Wq_ * u2h2((unsigned)xh_.y); \
    t12 += Wq_ * u2h2((unsigned)xh_.z); t13 += Wq_ * u2h2((unsigned)xh_.w); \
} while (0)

__global__ __launch_bounds__(256, 4) void fused_kernel(
        const float* __restrict__ b_off, const float* __restrict__ bias,
        float* ws, float* __restrict__ out) {
    __shared__ __align__(16) char shmem[37376];
    char* region = shmem;                                // [0,28160) F1 (176B rows)
    int2* scratch2 = (int2*)(shmem + 28160);             // [28160,31232) F1
    _Float16* Pl = (_Float16*)(shmem + 31232);           // [96][32] fp16
    float* pbuf = (float*)shmem;                         // epilogue overlay
    float* rsumS = (float*)(shmem + 8704);               // [32]
    float* rsqS  = (float*)(shmem + 8832);               // [32]

    int tid = threadIdx.x, wave = tid >> 6, lane = tid & 63;
    int col = lane & 15, quad = lane >> 4;
    int bid = blockIdx.x;
    int pi = bid >> 7, tile = bid & 127;
    int pid = pi >> 2, pih = (pi >> 1) & 1, piw = pi & 1;
    int qd0 = (tile >> 4) << 1;                          // 0..14 step 2
    int qh0 = ((tile >> 1) & 7) << 1;                    // 0..14 step 2
    int qw0 = (tile & 1) << 3;                           // 0 or 8

    const char* xtb = (const char*)(ws + WS_XT);
    const half8* wa8 = (const half8*)(ws + WS_WA);
    float* gstat = ws + WS_STAT;

    // ===================== F0: parity-collapsed offset GEMM -> P_lds ======
    {
        int4* ab4 = (int4*)shmem;                        // dbuf [0,24576)
        const _Float16* abuf16 = (const _Float16*)shmem;
        const int4* wsrc = (const int4*)(ws + WS_W2) + pi * 6144;
        int nsub = wave & 1, kh = wave >> 1;
        int vv = nsub * 16 + col;
        int qdv = qd0 + (vv >> 4), qhv = qh0 + ((vv >> 3) & 1), qwv = qw0 + (vv & 7);

        // preload all 8 B-frags (independent -> full ILP, none in loop)
        int4 bx[8];
#pragma unroll
        for (int tap = 0; tap < 8; tap++) {
            int cd = tap >> 2, ch = (tap >> 1) & 1, cw = tap & 1;
            int cell = ((qdv + cd + pid) * 18 + (qhv + ch + pih)) * 18 + (qwv + cw + piw);
            bx[tap] = *(const int4*)(xtb + cell * 128 + kh * 64 + quad * 16);
        }

        // prologue: stage tap 0, preload tap 1
        int4 ra0 = wsrc[tid], ra1 = wsrc[256 + tid], ra2 = wsrc[512 + tid];
        ab4[tid] = ra0; ab4[256 + tid] = ra1; ab4[512 + tid] = ra2;
        ra0 = wsrc[768 + tid]; ra1 = wsrc[768 + 256 + tid]; ra2 = wsrc[768 + 512 + tid];
        __syncthreads();

        floatx4 acc[6];
#pragma unroll
        for (int mt = 0; mt < 6; mt++) acc[mt] = (floatx4){0.f, 0.f, 0.f, 0.f};

        int fb = (kh * 4 + quad) * 768 + col * 8;

#pragma unroll
        for (int tap = 0; tap < 8; tap++) {
            if (tap < 7) {
                int4* dst = ab4 + ((tap + 1) & 1) * 768;
                dst[tid] = ra0; dst[256 + tid] = ra1; dst[512 + tid] = ra2;
            }
            if (tap < 6) {
                const int4* s2 = wsrc + (tap + 2) * 768;
                ra0 = s2[tid]; ra1 = s2[256 + tid]; ra2 = s2[512 + tid];
            }
            half8 bfrag = __builtin_bit_cast(half8, bx[tap]);
            const _Float16* abh = abuf16 + (tap & 1) * 6144;
#pragma unroll
            for (int mt = 0; mt < 6; mt++) {
                half8 af = *(const half8*)(abh + fb + mt * 128);
                acc[mt] = __builtin_amdgcn_mfma_f32_16x16x32_f16(af, bfrag, acc[mt], 0, 0, 0);
            }
            __syncthreads();
        }

        // kh reduce through LDS (abuf dead after loop-end barrier)
        float* red = (float*)shmem;                      // [(nsub*96+m)*17+col]
        if (kh == 1) {
#pragma unroll
            for (int mt = 0; mt < 6; mt++)
#pragma unroll
                for (int r = 0; r < 4; r++)
                    red[(nsub * 96 + mt * 16 + quad * 4 + r) * 17 + col] = acc[mt][r];
        }
        __syncthreads();
        if (kh == 0) {
#pragma unroll
            for (int mt = 0; mt < 6; mt++)
#pragma unroll
                for (int r = 0; r < 4; r++) {
                    int m = mt * 16 + quad * 4 + r;
                    if (m < 81)
                        Pl[m * 32 + vv] = (_Float16)(acc[mt][r]
                                         + red[(nsub * 96 + m) * 17 + col] + b_off[m]);
                }
        }
        __syncthreads();   // P_lds ready; red/abuf dead -> region staging
    }

    // ===================== F1: deform on 4x4x10 region (176B rows) ========
    // region row r = (rd*4+rh)*10+rw, r in [0,160); storage stride 176 B.
#pragma unroll 1
    for (int it = 0; it < 5; it++) {
        int i = it * 256 + tid;                          // 1280 = 5*256 exact
        int r = i >> 3, c16 = i & 7;
        int rd = r / 40, rem = r - rd * 40, rh = rem / 10, rw = rem - rh * 10;
        int cell = ((qd0 + rd) * 18 + (qh0 + rh)) * 18 + (qw0 + rw);
        int4 vsrc = *(const int4*)(xtb + cell * 128 + c16 * 16);
        *(int4*)(region + r * 176 + c16 * 16) = vsrc;
    }
    __syncthreads();

    int vh = wave & 1, kt = wave >> 1;
    int v = vh * 16 + col;
    int qdv = qd0 + (v >> 4), qhv = qh0 + ((v >> 3) & 1), qwv = qw0 + (v & 7);
    int dcoord = 2 * qdv + pid, hcoord = 2 * qhv + pih, wcoord = 2 * qwv + piw;
    int gvox = dcoord * 1024 + hcoord * 32 + wcoord;
    int tbeg = kt ? 14 : 0, tend = kt ? 27 : 14;
    int subLo = quad * 16, subHi = subLo + 64;
    int bd = quad >> 1, bh = quad & 1;

    floatx4 acc0 = {0.f, 0.f, 0.f, 0.f}, acc1 = {0.f, 0.f, 0.f, 0.f};

    float od = (float)Pl[(3 * tbeg + 0) * 32 + v];
    float oh = (float)Pl[(3 * tbeg + 1) * 32 + v];
    float ow = (float)Pl[(3 * tbeg + 2) * 32 + v];

#pragma unroll 1
    for (int tap = tbeg; tap < tend; tap++) {
        int kd = tap / 9, r9 = tap - kd * 9, kh2 = r9 / 3, kw2 = r9 - kh2 * 3;
        float pdc = (float)(dcoord + kd - 1) + od;
        float phc = (float)(hcoord + kh2 - 1) + oh;
        float pwc = (float)(wcoord + kw2 - 1) + ow;
        float fd0 = floorf(pdc), fh0 = floorf(phc), fw0 = floorf(pwc);
        float fd = pdc - fd0, fh = phc - fh0, fw = pwc - fw0;
        int id = (int)fd0, ih = (int)fh0, iw = (int)fw0;

        int cd0 = ((min(max(id,     -2), 33)) >> 1) + 1;
        int cd1 = ((min(max(id + 1, -2), 33)) >> 1) + 1;
        int ch0 = ((min(max(ih,     -2), 33)) >> 1) + 1;
        int ch1 = ((min(max(ih + 1, -2), 33)) >> 1) + 1;
        int cw0 = ((min(max(iw,     -2), 33)) >> 1) + 1;
        int cw1 = ((min(max(iw + 1, -2), 33)) >> 1) + 1;
        int sd0 = cd0 - qd0, sd1 = cd1 - qd0;
        int sh0 = ch0 - qh0, sh1 = ch1 - qh0;
        int sw0 = cw0 - qw0, sw1 = cw1 - qw0;
        bool oob = ((unsigned)sd0 > 3u) | ((unsigned)sd1 > 3u)
                 | ((unsigned)sh0 > 3u) | ((unsigned)sh1 > 3u)
                 | ((unsigned)sw0 > 9u) | ((unsigned)sw1 > 9u);

        // this lane builds corners (bd,bh,0) and (bd,bh,1)
        int sdq = bd ? sd1 : sd0, shq = bh ? sh1 : sh0;
        int rb = (sdq * 4 + shq) * 10;
        int r0 = rb + sw0, r1 = rb + sw1;
        int a0 = oob ? 0x8000 : (r0 * 176);
        int a1 = oob ? 0x8000 : (r1 * 176);
        float gdw = 1.f - fd, ghw = 1.f - fh, gww = 1.f - fw;
        float wd = bd ? fd : gdw, wh = bh ? fh : ghw;
        float wdh = wd * wh;
        unsigned wb0 = (unsigned)__builtin_bit_cast(unsigned short, (_Float16)(wdh * gww));
        unsigned wb1 = (unsigned)__builtin_bit_cast(unsigned short, (_Float16)(wdh * fw));
        scratch2[(wave * 16 + col) * 6 + quad] =
            make_int2(a0 | (a1 << 16), (int)(wb0 | (wb1 << 16)));

        if (tap + 1 < tend) {
            od = (float)Pl[(3 * tap + 3) * 32 + v];
            oh = (float)Pl[(3 * tap + 4) * 32 + v];
            ow = (float)Pl[(3 * tap + 5) * 32 + v];
        }

        int kb = tap * 8 + quad;
        half8 a00 = wa8[kb * 32 + col];
        half8 a01 = wa8[kb * 32 + 16 + col];
        half8 a10 = wa8[(kb + 4) * 32 + col];
        half8 a11 = wa8[(kb + 4) * 32 + 16 + col];

        const int4* sc = (const int4*)(scratch2 + (wave * 16 + col) * 6);
        int4 p0 = sc[0], p1 = sc[1];

        half2v s00 = {0, 0}, s01 = {0, 0}, s02 = {0, 0}, s03 = {0, 0};
        half2v s10 = {0, 0}, s11 = {0, 0}, s12 = {0, 0}, s13 = {0, 0};
        DO2(p0.x, p0.y); DO2(p0.z, p0.w);
        DO2(p1.x, p1.y); DO2(p1.z, p1.w);

        if (__any((p0.x & 0x8000) != 0)) {
            bool flg = (p0.x & 0x8000) != 0;
            int Rd0 = ((min(max(id,     -2), 33) >> 1) + 1) * (324 * 128);
            int Rd1 = ((min(max(id + 1, -2), 33) >> 1) + 1) * (324 * 128);
            int Rh0 = ((min(max(ih,     -2), 33) >> 1) + 1) * (18 * 128);
            int Rh1 = ((min(max(ih + 1, -2), 33) >> 1) + 1) * (18 * 128);
            int Rw0 = ((min(max(iw,     -2), 33) >> 1) + 1) * 128;
            int Rw1 = ((min(max(iw + 1, -2), 33) >> 1) + 1) * 128;
            half2v t00 = {0,0}, t01 = {0,0}, t02 = {0,0}, t03 = {0,0};
            half2v t10 = {0,0}, t11 = {0,0}, t12 = {0,0}, t13 = {0,0};
            GSLOW(Rd0 + Rh0 + Rw0, gdw * ghw * gww);
            GSLOW(Rd0 + Rh0 + Rw1, gdw * ghw * fw);
            GSLOW(Rd0 + Rh1 + Rw0, gdw * fh  * gww);
            GSLOW(Rd0 + Rh1 + Rw1, gdw * fh  * fw);
            GSLOW(Rd1 + Rh0 + Rw0, fd  * ghw * gww);
            GSLOW(Rd1 + Rh0 + Rw1, fd  * ghw * fw);
            GSLOW(Rd1 + Rh1 + Rw0, fd  * fh  * gww);
            GSLOW(Rd1 + Rh1 + Rw1, fd  * fh  * fw);
            s00 = flg ? t00 : s00; s01 = flg ? t01 : s01;
            s02 = flg ? t02 : s02; s03 = flg ? t03 : s03;
            s10 = flg ? t10 : s10; s11 = flg ? t11 : s11;
            s12 = flg ? t12 : s12; s13 = flg ? t13 : s13;
        }

        half8 bf0 = pk8(s00, s01, s02, s03);
        half8 bf1 = pk8(s10, s11, s12, s13);

        acc0 = __builtin_amdgcn_mfma_f32_16x16x32_f16(a00, bf0, acc0, 0, 0, 0);
        acc1 = __builtin_amdgcn_mfma_f32_16x16x32_f16(a01, bf0, acc1, 0, 0, 0);
        acc0 = __builtin_amdgcn_mfma_f32_16x16x32_f16(a10, bf1, acc0, 0, 0, 0);
        acc1 = __builtin_amdgcn_mfma_f32_16x16x32_f16(a11, bf1, acc1, 0, 0, 0);
    }

    // ---- epilogue: region dead -> overlay pbuf/rsum ----
    __syncthreads();
    if (kt == 1) {
#pragma unroll
        for (int r = 0; r < 4; r++) {
            pbuf[((vh * 2 + 0) * 16 + quad * 4 + r) * 17 + col] = acc0[r];
            pbuf[((vh * 2 + 1) * 16 + quad * 4 + r) * 17 + col] = acc1[r];
        }
    }
    if (tid < 64) ((float*)(shmem + 8704))[tid] = 0.f;   // zero rsumS+rsqS
    __syncthreads();
    if (kt == 0) {
#pragma unroll
        for (int r = 0; r < 4; r++) {
            int i = quad * 4 + r;
            int o0 = i;
            float v0 = acc0[r] + pbuf[((vh * 2 + 0) * 16 + i) * 17 + col] + bias[o0];
            out[o0 * NVOX + gvox] = v0;
            atomicAdd(&rsumS[o0], v0);
            atomicAdd(&rsqS[o0], v0 * v0);
            int o1 = 16 + i;
            float v1 = acc1[r] + pbuf[((vh * 2 + 1) * 16 + i) * 17 + col] + bias[o1];
            out[o1 * NVOX + gvox] = v1;
            atomicAdd(&rsumS[o1], v1);
            atomicAdd(&rsqS[o1], v1 * v1);
        }
    }
    __syncthreads();
    if (tid < COUT) {
        atomicAdd(&gstat[tid], rsumS[tid]);
        atomicAdd(&gstat[COUT + tid], rsqS[tid]);
    }
}

// ---------------------------------------------------------------------------
// BN finalize + ReLU, in-place, float4-vectorized (1024 blocks).
// ---------------------------------------------------------------------------
__global__ void bn_kernel(const float* __restrict__ ws,
                          const float* __restrict__ gamma,
                          const float* __restrict__ beta,
                          float* out) {
    int i = blockIdx.x * 256 + threadIdx.x;   // float4 index
    int o = i >> 13;                          // 8192 float4 per channel
    const float* gstat = ws + WS_STAT;
    const float inv = 1.f / 32768.f;
    float mean = gstat[o] * inv;
    float var  = gstat[COUT + o] * inv - mean * mean;
    float sc   = rsqrtf(var + 1e-5f) * gamma[o];
    float bt   = beta[o];
    float4 v = ((float4*)out)[i];
    v.x = fmaxf((v.x - mean) * sc + bt, 0.f);
    v.y = fmaxf((v.y - mean) * sc + bt, 0.f);
    v.z = fmaxf((v.z - mean) * sc + bt, 0.f);
    v.w = fmaxf((v.w - mean) * sc + bt, 0.f);
    ((float4*)out)[i] = v;
}

// ---------------------------------------------------------------------------
extern "C" void kernel_launch(void* const* d_in, const int* in_sizes, int n_in,
                              void* d_out, int out_size, void* d_ws, size_t ws_size,
                              hipStream_t stream) {
    const float* x     = (const float*)d_in[0];
    const float* w_off = (const float*)d_in[1];
    const float* b_off = (const float*)d_in[2];
    const float* wmat  = (const float*)d_in[3];
    const float* bias  = (const float*)d_in[4];
    const float* gamma = (const float*)d_in[5];
    const float* beta  = (const float*)d_in[6];
    float* ws  = (float*)d_ws;
    float* out = (float*)d_out;

    prep_all_kernel<<<312, 256, 0, stream>>>(x, w_off, wmat, ws);
    fused_kernel<<<1024, 256, 0, stream>>>(b_off, bias, ws, out);
    bn_kernel<<<1024, 256, 0, stream>>>(ws, gamma, beta, out);
}